// Round 5
// baseline (564.416 us; speedup 1.0000x reference)
//
#include <hip/hip_runtime.h>
#include <hip/hip_bf16.h>

// ---------------------------------------------------------------------------
// Quantum ViT: B=128, T=127, D_IN=48, DK=S=128, H=8, L=6, P=8128
// Inputs: all float32. Output: float32 [B, DK]. bf16 MFMA internals.
//
// R17: revert to R13's proven attn body (43.5us; sH LDS-staged, global
// B-frags only for weights) after the R14-R16 frag-major-h arc proved
// global-operand MFMA is latency-bound at 2 blocks/CU. Two deltas vs R13:
//  (1) __launch_bounds__(512, 2): LDS caps occupancy at 2 blocks/CU anyway;
//      the old (512,4) pinned VGPR=64 (acc+hres alone), leaving no registers
//      to pipeline the 8 B-frag loads per k-step in phases A/C.
//  (2) Phase C hoisted BEFORE softmax into acc2: C's MFMAs/loads drain in
//      the matrix/memory pipes while softmax VALU (depends only on B's acc)
//      executes. acc2 first read after barrier B4 -> free overlap.
// Kept from R13: frag-major wt/cvwf, no Wt staging, one-wave last layer,
// tiny last merge, setprio.
// ---------------------------------------------------------------------------

typedef __bf16 bf16x8 __attribute__((ext_vector_type(8)));
typedef float  f32x4  __attribute__((ext_vector_type(4)));
typedef unsigned int u32;

// swizzled LDS index for a 128x128 bf16 tile: chunk(col/8) ^= row&15.
__device__ __forceinline__ int sidx(int row, int col)
{
    return row * 128 + ((((col >> 3) ^ (row & 15)) << 3) | (col & 7));
}

// async global->LDS 16B per lane; LDS dest must be wave-uniform base.
__device__ __forceinline__ void gll16(const void* g, void* l)
{
    __builtin_amdgcn_global_load_lds(
        (const __attribute__((address_space(1))) void*)g,
        (__attribute__((address_space(3))) void*)l, 16, 0, 0);
}

// ---------------------------------------------------------------------------
// 0) prep: [0..3071] sincos table (layer-major, 256 layers, pad=identity)
//          [3072..3455] Vw f32 -> bf16 fragment-major
// ---------------------------------------------------------------------------
__global__ void __launch_bounds__(256)
prep_kernel(const float* __restrict__ phi, float2* __restrict__ csn,
            const float* __restrict__ vw,  __bf16* __restrict__ cvwf)
{
    if (blockIdx.x < 3072) {
        const int mat = blockIdx.x >> 6;
        const int t   = ((blockIdx.x & 63) << 2) + (threadIdx.x >> 6);
        const int j   = threadIdx.x & 63;
        float th = 0.f;
        if (t < 253) {
            const int p = t & 1, i = 2 * j + p;
            const int lim = min(t, 252 - t);
            if (i <= lim) {
                const int k = (t + i) >> 1;
                th = phi[mat * 8128 + ((k * (k + 1)) >> 1) + (k - i)];
            }
        }
        float sn, cs;
        __sincosf(th, &sn, &cs);
        csn[(mat * 256 + t) * 64 + j] = make_float2(cs, sn);
    } else {
        const int f    = (blockIdx.x - 3072) * 256 + threadIdx.x;  // 98304 frags
        const int lane = f & 63;
        const int k0   = (f >> 6) & 3;
        const int t    = (f >> 8) & 7;
        const int lh   = f >> 11;
        const int row  = t * 16 + (lane & 15);
        const int col  = k0 * 32 + (lane >> 4) * 8;
        const float* src = vw + (lh * 128 + row) * 128 + col;
        __bf16* dst = cvwf + f * 8;
#pragma unroll
        for (int j2 = 0; j2 < 8; j2++) dst[j2] = (__bf16)src[j2];
    }
}

// ---------------------------------------------------------------------------
// 1) W build: 253 parallel Givens layers (time(k,i)=2k-i), 16-layer groups,
//    3-slot register buffer, prefetch 2 groups ahead. 4 cols/block.
//    Output: FRAGMENT-MAJOR Wt (B-operand frags, same layout as cvwf).
// ---------------------------------------------------------------------------
__global__ void __launch_bounds__(64)
build_w_kernel(const float2* __restrict__ csn, __bf16* __restrict__ wt)
{
    const int mat = blockIdx.x >> 5;
    const int grp = blockIdx.x & 31;
    const int c0  = grp * 4;
    const int lam = threadIdx.x;

    const float2* base = csn + (mat * 256) * 64 + lam;

    float vlo[4], vhi[4];
#pragma unroll
    for (int j = 0; j < 4; j++) {
        vlo[j] = (2 * lam     == c0 + j) ? 1.f : 0.f;
        vhi[j] = (2 * lam + 1 == c0 + j) ? 1.f : 0.f;
    }

    float2 buf[3][16];
#pragma unroll
    for (int k = 0; k < 16; k++) buf[0][k] = base[k * 64];
#pragma unroll
    for (int k = 0; k < 16; k++) buf[1][k] = base[(16 + k) * 64];

#pragma unroll
    for (int g = 0; g < 16; g++) {
        const int cb = g % 3;
        if (g < 14) {
            const int nb = (g + 2) % 3;
#pragma unroll
            for (int k = 0; k < 16; k++)
                buf[nb][k] = base[((g + 2) * 16 + k) * 64];
        }
#pragma unroll
        for (int p = 0; p < 8; p++) {
            {
                const float cs = buf[cb][2 * p].x, sn = buf[cb][2 * p].y;
#pragma unroll
                for (int j = 0; j < 4; j++) {
                    float lo = vlo[j], hi = vhi[j];
                    vlo[j] = cs * lo - sn * hi;
                    vhi[j] = sn * lo + cs * hi;
                }
            }
            {
                const float cs = buf[cb][2 * p + 1].x, sn = buf[cb][2 * p + 1].y;
#pragma unroll
                for (int j = 0; j < 4; j++) {
                    float y  = __shfl_down(vlo[j], 1);
                    float x  = vhi[j];
                    float xn = cs * x - sn * y;
                    float yn = sn * x + cs * y;
                    vhi[j] = xn;
                    float z = __shfl_up(yn, 1);
                    if (lam > 0) vlo[j] = z;
                }
            }
        }
    }

    const int t    = c0 >> 4;
    const int k0w  = lam >> 4;
    const int quad = (lam >> 2) & 3;
    u32* wtu = (u32*)wt;
#pragma unroll
    for (int j = 0; j < 4; j++) {
        __bf16 va = (__bf16)vlo[j];
        __bf16 vb = (__bf16)vhi[j];
        u32 pk = (u32)__builtin_bit_cast(unsigned short, va)
               | ((u32)__builtin_bit_cast(unsigned short, vb) << 16);
        const int frag = (t * 4 + k0w) * 64 + quad * 16 + ((c0 & 15) + j);
        wtu[mat * 8192 + frag * 4 + (lam & 3)] = pk;
    }
}

// ---------------------------------------------------------------------------
// 2) embed: 512 thr = 4 tokens/block (ew read once per block via L1).
//    LN0 -> hf (f32), hb (bf16 linear), invn = rsqrt(Sum h^2).
// ---------------------------------------------------------------------------
__global__ void __launch_bounds__(512)
embed_kernel(const float* __restrict__ x,  const float* __restrict__ ew,
             const float* __restrict__ eb, const float* __restrict__ ct,
             const float* __restrict__ g0, const float* __restrict__ b0,
             float* __restrict__ hf, __bf16* __restrict__ hb,
             float* __restrict__ invn)
{
    __shared__ float sx[4][48];
    __shared__ float sred[4][2];
    const int d  = threadIdx.x & 127, sq = threadIdx.x >> 7;
    const int wh = (threadIdx.x >> 6) & 1;
    const int b  = blockIdx.x & 127;
    const int s  = (blockIdx.x >> 7) * 4 + sq;

    if (s > 0 && d < 48) sx[sq][d] = x[(b * 127 + (s - 1)) * 48 + d];
    __syncthreads();

    float val;
    if (s == 0) {
        val = ct[d];
    } else {
        float aa = 0.f;
#pragma unroll
        for (int f = 0; f < 48; f++) aa = fmaf(sx[sq][f], ew[d * 48 + f], aa);
        val = aa + eb[d];
    }
    float v = val;
#pragma unroll
    for (int m = 32; m; m >>= 1) v += __shfl_xor(v, m);
    if ((threadIdx.x & 63) == 0) sred[sq][wh] = v;
    __syncthreads();
    float mean = (sred[sq][0] + sred[sq][1]) * (1.f / 128.f);
    float xc   = val - mean;
    __syncthreads();
    v = xc * xc;
#pragma unroll
    for (int m = 32; m; m >>= 1) v += __shfl_xor(v, m);
    if ((threadIdx.x & 63) == 0) sred[sq][wh] = v;
    __syncthreads();
    float var = (sred[sq][0] + sred[sq][1]) * (1.f / 128.f);
    float y   = xc * rsqrtf(var + 1e-5f) * g0[d] + b0[d];
    __syncthreads();
    v = y * y;
#pragma unroll
    for (int m = 32; m; m >>= 1) v += __shfl_xor(v, m);
    if ((threadIdx.x & 63) == 0) sred[sq][wh] = v;
    __syncthreads();
    float ss = sred[sq][0] + sred[sq][1];

    const int o = (b * 128 + s) * 128 + d;
    hf[o] = y;
    hb[o] = (__bf16)y;
    if (d == 0) invn[b * 128 + s] = rsqrtf(ss);
}

// ---------------------------------------------------------------------------
// 3) fused attention head (R13 body + C-overlap): one WG per (head, batch).
//    512 thr = 8 waves, wave w owns rows w*16..w*16+15.
//    A: T1 = h @ W (A: sH, B: wt frags global) -> sY (wave-private)
//    B: G = T1 @ h^T (A: sY, B: sH)
//    C: V = h @ Vw^T (A: sH, B: cvwf frags global) -> acc2   [issued pre-
//       softmax; MFMAs drain under softmax VALU]
//    softmax -> Pm -> sY ; hres prefetch
//    B4; V^T (acc2) -> sH; B5
//    D: O = Pm @ V (A: sY, B: sH), +h, LN, *mw -> hs
//    last==1: only wave 7 runs A/B/softmax/D; stores row 127.
// ---------------------------------------------------------------------------
__global__ void __launch_bounds__(512, 2)
attn_kernel(int l, int last,
            const float*  __restrict__ hf,  const __bf16* __restrict__ hb,
            const float*  __restrict__ invn, const __bf16* __restrict__ wt,
            const __bf16* __restrict__ vwf, const float* __restrict__ vb,
            const float* __restrict__ lng,  const float* __restrict__ lnb,
            const float* __restrict__ mwp,  __bf16* __restrict__ hs)
{
    __shared__ __align__(16) __bf16 sH[128 * 128];
    __shared__ __align__(16) __bf16 sY[128 * 128];
    __shared__ float sInv[128];
    __shared__ float sVb[128];
    __shared__ float sLg[128];
    __shared__ float sLb[128];

    const int tid  = threadIdx.x;
    const int lane = tid & 63, w = tid >> 6;
    const int l15  = lane & 15, quad = lane >> 4;
    const int b    = blockIdx.x & 127;   // XCD = b%8
    const int hh   = blockIdx.x >> 7;
    const int lh   = l * 8 + hh;

    const __bf16* hbp   = hb  + b * 16384;
    const __bf16* wbase = wt  + (size_t)lh * 16384;
    const __bf16* vbase = vwf + (size_t)lh * 16384;

    // ---- stage sH: async direct-to-LDS; linear dest, inverse-swz source ----
#pragma unroll
    for (int c = 0; c < 4; c++) {
        const int ch  = tid + c * 512;           // this lane's LDS chunk
        const int row = ch >> 4, cc = ch & 15;
        const int sc  = cc ^ (row & 15);         // inverse swizzle (involution)
        gll16(hbp + (row * 16 + sc) * 8, &sH[(c * 512 + w * 64) * 8]);
    }
    if (tid < 128) {
        sInv[tid] = invn[b * 128 + tid];
        sVb[tid]  = vb[lh * 128 + tid];
        sLg[tid]  = lng[lh * 128 + tid];
        sLb[tid]  = lnb[lh * 128 + tid];
    }
    __syncthreads();  // B1 (drains global_load_lds via vmcnt(0))

    const int r0 = w * 16;
    const int kq = quad * 8;
    const int q4 = quad * 4;
    const f32x4 vzero = {0.f, 0.f, 0.f, 0.f};
    const bool active = !last || (w == 7);

    f32x4 acc[8];
    f32x4 acc2[8];
    float hres[8][4];

    // A-frags from sH (LDS), B-frags fragment-major from global -> acc
    auto mmGA = [&](const __bf16* gB) {
#pragma unroll
        for (int t = 0; t < 8; t++) acc[t] = vzero;
        __builtin_amdgcn_s_setprio(1);
#pragma unroll
        for (int k0c = 0; k0c < 4; k0c++) {
            bf16x8 a0 = *(const bf16x8*)(&sH[sidx(r0 + l15, k0c * 32 + kq)]);
#pragma unroll
            for (int t = 0; t < 8; t++) {
                bf16x8 bb = *(const bf16x8*)(gB + ((t * 4 + k0c) * 64 + lane) * 8);
                acc[t] = __builtin_amdgcn_mfma_f32_16x16x32_bf16(a0, bb, acc[t], 0, 0, 0);
            }
        }
        __builtin_amdgcn_s_setprio(0);
    };

    // same but -> acc2 (phase C, overlapped under softmax)
    auto mmGC = [&](const __bf16* gB) {
#pragma unroll
        for (int t = 0; t < 8; t++) acc2[t] = vzero;
        __builtin_amdgcn_s_setprio(1);
#pragma unroll
        for (int k0c = 0; k0c < 4; k0c++) {
            bf16x8 a0 = *(const bf16x8*)(&sH[sidx(r0 + l15, k0c * 32 + kq)]);
#pragma unroll
            for (int t = 0; t < 8; t++) {
                bf16x8 bb = *(const bf16x8*)(gB + ((t * 4 + k0c) * 64 + lane) * 8);
                acc2[t] = __builtin_amdgcn_mfma_f32_16x16x32_bf16(a0, bb, acc2[t], 0, 0, 0);
            }
        }
        __builtin_amdgcn_s_setprio(0);
    };

    // A-frags from LDS (own rows), B-frags from LDS (all rows) -> acc
    auto mmLL = [&](const __bf16* Ab, const __bf16* Bb) {
#pragma unroll
        for (int t = 0; t < 8; t++) acc[t] = vzero;
        __builtin_amdgcn_s_setprio(1);
#pragma unroll
        for (int k0 = 0; k0 < 128; k0 += 32) {
            const int kk = k0 + kq;
            bf16x8 a0 = *(const bf16x8*)(&Ab[sidx(r0 + l15, kk)]);
#pragma unroll
            for (int t = 0; t < 8; t++) {
                bf16x8 bb = *(const bf16x8*)(&Bb[sidx(t * 16 + l15, kk)]);
                acc[t] = __builtin_amdgcn_mfma_f32_16x16x32_bf16(a0, bb, acc[t], 0, 0, 0);
            }
        }
        __builtin_amdgcn_s_setprio(0);
    };

    if (active) {
        // ========= Phase A: T1 = h @ W =========
        mmGA(wbase);
#pragma unroll
        for (int t = 0; t < 8; t++)
#pragma unroll
            for (int r = 0; r < 4; r++)
                sY[sidx(r0 + q4 + r, t * 16 + l15)] = (__bf16)acc[t][r];
        // no barrier: phase B reads only this wave's own T1 rows

        // ========= Phase B: G = T1 @ h^T =========
        mmLL(sY, sH);
    }

    // ========= Phase C (all waves, into acc2; drains under softmax) ======
    mmGC(vbase);

    if (active) {
        // ---- softmax (base 2): v = G^2*inv_s*inv_t*(scale*log2e) -> Pm ----
        const float scale2 = 0.08838834764831843f * 1.4426950408889634f;
        float invt[8];
#pragma unroll
        for (int t = 0; t < 8; t++) invt[t] = sInv[t * 16 + l15];
        float invs[4];
#pragma unroll
        for (int r = 0; r < 4; r++) invs[r] = sInv[r0 + q4 + r];

        float mx[4] = {-3e38f, -3e38f, -3e38f, -3e38f};
#pragma unroll
        for (int t = 0; t < 8; t++)
#pragma unroll
            for (int r = 0; r < 4; r++) {
                float g = acc[t][r];
                float v = g * g * invs[r] * invt[t] * scale2;
                acc[t][r] = v;
                mx[r] = fmaxf(mx[r], v);
            }
#pragma unroll
        for (int m = 1; m < 16; m <<= 1)
#pragma unroll
            for (int r = 0; r < 4; r++) mx[r] = fmaxf(mx[r], __shfl_xor(mx[r], m));

        float sm[4] = {0.f, 0.f, 0.f, 0.f};
#pragma unroll
        for (int t = 0; t < 8; t++)
#pragma unroll
            for (int r = 0; r < 4; r++) {
                float e = exp2f(acc[t][r] - mx[r]);
                acc[t][r] = e;
                sm[r] += e;
            }
#pragma unroll
        for (int m = 1; m < 16; m <<= 1)
#pragma unroll
            for (int r = 0; r < 4; r++) sm[r] += __shfl_xor(sm[r], m);
#pragma unroll
        for (int r = 0; r < 4; r++) sm[r] = 1.0f / sm[r];
#pragma unroll
        for (int t = 0; t < 8; t++)
#pragma unroll
            for (int r = 0; r < 4; r++)
                sY[sidx(r0 + q4 + r, t * 16 + l15)] = (__bf16)(acc[t][r] * sm[r]);

        // residual prefetch (consumed in epilogue; hides under B4/B5/D)
        const float* hfp = hf + (b * 128 + r0 + q4) * 128;
#pragma unroll
        for (int t = 0; t < 8; t++)
#pragma unroll
            for (int r = 0; r < 4; r++)
                hres[t][r] = hfp[r * 128 + t * 16 + l15];
    }

    __syncthreads();  // B4: all waves done reading sH (phases B & C)

    {   // V^T into sH: sH[e][token]
        float vbv[8];
#pragma unroll
        for (int t = 0; t < 8; t++) vbv[t] = sVb[t * 16 + l15];
#pragma unroll
        for (int t = 0; t < 8; t++)
#pragma unroll
            for (int r = 0; r < 4; r++)
                sH[sidx(t * 16 + l15, r0 + q4 + r)] = (__bf16)(acc2[t][r] + vbv[t]);
    }
    __syncthreads();  // B5

    if (active) {
        // ========= Phase D: O = Pm @ V =========
        mmLL(sY, sH);

        {   // epilogue: +h, LN over d, *merger_w -> hs
            const float mw = mwp[lh];
            float lgv[8], lbv[8];
#pragma unroll
            for (int t = 0; t < 8; t++) {
                lgv[t] = sLg[t * 16 + l15];
                lbv[t] = sLb[t * 16 + l15];
            }
            float sum_[4] = {0.f, 0.f, 0.f, 0.f};
            float sq_[4]  = {0.f, 0.f, 0.f, 0.f};
#pragma unroll
            for (int t = 0; t < 8; t++)
#pragma unroll
                for (int r = 0; r < 4; r++) {
                    float xx = acc[t][r] + hres[t][r];
                    acc[t][r] = xx;
                    sum_[r] += xx;
                    sq_[r]  += xx * xx;
                }
#pragma unroll
            for (int m = 1; m < 16; m <<= 1)
#pragma unroll
                for (int r = 0; r < 4; r++) {
                    sum_[r] += __shfl_xor(sum_[r], m);
                    sq_[r]  += __shfl_xor(sq_[r], m);
                }
            float mean[4], rstd[4];
#pragma unroll
            for (int r = 0; r < 4; r++) {
                mean[r] = sum_[r] * (1.f / 128.f);
                float var = sq_[r] * (1.f / 128.f) - mean[r] * mean[r];
                rstd[r] = rsqrtf(fmaxf(var, 0.f) + 1e-5f);
            }
            __bf16* hsp = hs + ((hh * 128 + b) * 128 + r0 + q4) * 128;
#pragma unroll
            for (int t = 0; t < 8; t++)
#pragma unroll
                for (int r = 0; r < 4; r++) {
                    if (!last || (q4 + r == 15)) {
                        float y = (acc[t][r] - mean[r]) * rstd[r] * lgv[t] + lbv[t];
                        hsp[r * 128 + t * 16 + l15] = (__bf16)(y * mw);
                    }
                }
        }
    }
}

// ---------------------------------------------------------------------------
// 4) merge: one wave per token. Normal: 256 thr = 4 tokens/block, grid 4096.
//    last: grid 32, token 127 only, writes out only.
// ---------------------------------------------------------------------------
__global__ void __launch_bounds__(256)
merge_kernel(const __bf16* __restrict__ hs, const float* __restrict__ mbp, int l,
             float* __restrict__ hf, __bf16* __restrict__ hb, float* __restrict__ invn,
             float* __restrict__ out, int last)
{
    const int ln = threadIdx.x & 63;
    const int d2 = ln * 2;
    const float mbv = mbp[l];

    int b, s;
    if (last) {
        b = blockIdx.x * 4 + (threadIdx.x >> 6);
        s = 127;
    } else {
        b = blockIdx.x & 127;
        s = (blockIdx.x >> 7) * 4 + (threadIdx.x >> 6);
    }

    float a0 = mbv, a1 = mbv;
#pragma unroll
    for (int h8 = 0; h8 < 8; h8++) {
        const __bf16* p = hs + (((size_t)h8 * 128 + b) * 128 + s) * 128 + d2;
        a0 += (float)p[0];
        a1 += (float)p[1];
    }

    if (last) {
        *(float2*)(out + b * 128 + d2) = make_float2(a0, a1);
        return;
    }

    float v = a0 * a0 + a1 * a1;
#pragma unroll
    for (int m = 32; m; m >>= 1) v += __shfl_xor(v, m);   // Sum over all 128 d

    const size_t o = ((size_t)b * 128 + s) * 128 + d2;
    *(float2*)(hf + o) = make_float2(a0, a1);
    __bf16 p0 = (__bf16)a0, p1 = (__bf16)a1;
    ((u32*)hb)[o >> 1] = (u32)__builtin_bit_cast(unsigned short, p0)
                       | ((u32)__builtin_bit_cast(unsigned short, p1) << 16);
    if (ln == 0) invn[b * 128 + s] = rsqrtf(v);
}

// ---------------------------------------------------------------------------
extern "C" void kernel_launch(void* const* d_in, const int* in_sizes, int n_in,
                              void* d_out, int out_size, void* d_ws, size_t ws_size,
                              hipStream_t stream)
{
    (void)in_sizes; (void)n_in; (void)out_size; (void)ws_size;

    const float* x   = (const float*)d_in[0];
    const float* ew  = (const float*)d_in[1];
    const float* eb  = (const float*)d_in[2];
    const float* ct  = (const float*)d_in[3];
    const float* g0  = (const float*)d_in[4];
    const float* b0  = (const float*)d_in[5];
    const float* vw  = (const float*)d_in[6];
    const float* vb  = (const float*)d_in[7];
    const float* lng = (const float*)d_in[8];
    const float* lnb = (const float*)d_in[9];
    const float* phi = (const float*)d_in[10];
    const float* mw  = (const float*)d_in[11];
    const float* mb  = (const float*)d_in[12];
    float* out = (float*)d_out;

    char* ws = (char*)d_ws;
    __bf16* wt   = (__bf16*)(ws);                 //  1,572,864 (frag-major Wt)
    float*  hf   = (float*)(ws + 1572864);        //  8,388,608
    __bf16* hb   = (__bf16*)(ws + 9961472);       //  4,194,304 (linear bf16 h)
    float*  invn = (float*)(ws + 14155776);       //     65,536
    __bf16* hs   = (__bf16*)(ws + 14221312);      // 33,554,432
    __bf16* cvwf = (__bf16*)(ws + 47775744);      //  1,572,864 (frag-major Vw)
    float2* csn  = (float2*)(ws + 49348608);      //  6,291,456  (~55.6 MB)

    prep_kernel<<<3456, 256, 0, stream>>>(phi, csn, vw, cvwf);
    build_w_kernel<<<1536, 64, 0, stream>>>(csn, wt);
    embed_kernel<<<4096, 512, 0, stream>>>(x, ew, eb, ct, g0, b0, hf, hb, invn);
    for (int l = 0; l < 6; l++) {
        const int last = (l == 5) ? 1 : 0;
        attn_kernel<<<1024, 512, 0, stream>>>(l, last, hf, hb, invn, wt, cvwf,
                                              vb, lng, lnb, mw, hs);
        merge_kernel<<<last ? 32 : 4096, 256, 0, stream>>>(hs, mb, l, hf, hb,
                                                           invn, out, last);
    }
}

// Round 6
// 388.026 us; speedup vs baseline: 1.4546x; 1.4546x over previous
//
#include <hip/hip_runtime.h>
#include <hip/hip_bf16.h>

// ---------------------------------------------------------------------------
// Quantum ViT: B=128, T=127, D_IN=48, DK=S=128, H=8, L=6, P=8128
// Inputs: all float32. Output: float32 [B, DK]. bf16 MFMA internals.
//
// R18: verbatim R13 (session-best 388us: attn 43.5us with sH gll16-staged,
// frag-major wt/cvwf B-operands, C-after-softmax single-acc, lb(512,4),
// last-layer wave-7 path) + ONE change: vectorized merge.
//  - merge: 16 lanes/token, 8 d/lane -> bf16x8 (16B) hs loads, float4 hf
//    stores, 16B packed hb store. Grid 4096->1024 (last: 8).
// R14-R17 lessons (recorded): global-frag MFMA operands for h are latency-
// bound at 2 blocks/CU; acc2-hoist forces AGPR round-trips; lb(512,2)
// doesn't help this body. R13's attn config is the measured local optimum.
// ---------------------------------------------------------------------------

typedef __bf16 bf16x8 __attribute__((ext_vector_type(8)));
typedef float  f32x4  __attribute__((ext_vector_type(4)));
typedef unsigned int u32;
typedef u32 u32x4 __attribute__((ext_vector_type(4)));

// swizzled LDS index for a 128x128 bf16 tile: chunk(col/8) ^= row&15.
__device__ __forceinline__ int sidx(int row, int col)
{
    return row * 128 + ((((col >> 3) ^ (row & 15)) << 3) | (col & 7));
}

// async global->LDS 16B per lane; LDS dest must be wave-uniform base.
__device__ __forceinline__ void gll16(const void* g, void* l)
{
    __builtin_amdgcn_global_load_lds(
        (const __attribute__((address_space(1))) void*)g,
        (__attribute__((address_space(3))) void*)l, 16, 0, 0);
}

// ---------------------------------------------------------------------------
// 0) prep: [0..3071] sincos table (layer-major, 256 layers, pad=identity)
//          [3072..3455] Vw f32 -> bf16 fragment-major
// ---------------------------------------------------------------------------
__global__ void __launch_bounds__(256)
prep_kernel(const float* __restrict__ phi, float2* __restrict__ csn,
            const float* __restrict__ vw,  __bf16* __restrict__ cvwf)
{
    if (blockIdx.x < 3072) {
        const int mat = blockIdx.x >> 6;
        const int t   = ((blockIdx.x & 63) << 2) + (threadIdx.x >> 6);
        const int j   = threadIdx.x & 63;
        float th = 0.f;
        if (t < 253) {
            const int p = t & 1, i = 2 * j + p;
            const int lim = min(t, 252 - t);
            if (i <= lim) {
                const int k = (t + i) >> 1;
                th = phi[mat * 8128 + ((k * (k + 1)) >> 1) + (k - i)];
            }
        }
        float sn, cs;
        __sincosf(th, &sn, &cs);
        csn[(mat * 256 + t) * 64 + j] = make_float2(cs, sn);
    } else {
        const int f    = (blockIdx.x - 3072) * 256 + threadIdx.x;  // 98304 frags
        const int lane = f & 63;
        const int k0   = (f >> 6) & 3;
        const int t    = (f >> 8) & 7;
        const int lh   = f >> 11;
        const int row  = t * 16 + (lane & 15);
        const int col  = k0 * 32 + (lane >> 4) * 8;
        const float* src = vw + (lh * 128 + row) * 128 + col;
        __bf16* dst = cvwf + f * 8;
#pragma unroll
        for (int j2 = 0; j2 < 8; j2++) dst[j2] = (__bf16)src[j2];
    }
}

// ---------------------------------------------------------------------------
// 1) W build: 253 parallel Givens layers (time(k,i)=2k-i), 16-layer groups,
//    3-slot register buffer, prefetch 2 groups ahead. 4 cols/block.
//    Output: FRAGMENT-MAJOR Wt (B-operand frags, same layout as cvwf).
// ---------------------------------------------------------------------------
__global__ void __launch_bounds__(64)
build_w_kernel(const float2* __restrict__ csn, __bf16* __restrict__ wt)
{
    const int mat = blockIdx.x >> 5;
    const int grp = blockIdx.x & 31;
    const int c0  = grp * 4;
    const int lam = threadIdx.x;

    const float2* base = csn + (mat * 256) * 64 + lam;

    float vlo[4], vhi[4];
#pragma unroll
    for (int j = 0; j < 4; j++) {
        vlo[j] = (2 * lam     == c0 + j) ? 1.f : 0.f;
        vhi[j] = (2 * lam + 1 == c0 + j) ? 1.f : 0.f;
    }

    float2 buf[3][16];
#pragma unroll
    for (int k = 0; k < 16; k++) buf[0][k] = base[k * 64];
#pragma unroll
    for (int k = 0; k < 16; k++) buf[1][k] = base[(16 + k) * 64];

#pragma unroll
    for (int g = 0; g < 16; g++) {
        const int cb = g % 3;
        if (g < 14) {
            const int nb = (g + 2) % 3;
#pragma unroll
            for (int k = 0; k < 16; k++)
                buf[nb][k] = base[((g + 2) * 16 + k) * 64];
        }
#pragma unroll
        for (int p = 0; p < 8; p++) {
            {
                const float cs = buf[cb][2 * p].x, sn = buf[cb][2 * p].y;
#pragma unroll
                for (int j = 0; j < 4; j++) {
                    float lo = vlo[j], hi = vhi[j];
                    vlo[j] = cs * lo - sn * hi;
                    vhi[j] = sn * lo + cs * hi;
                }
            }
            {
                const float cs = buf[cb][2 * p + 1].x, sn = buf[cb][2 * p + 1].y;
#pragma unroll
                for (int j = 0; j < 4; j++) {
                    float y  = __shfl_down(vlo[j], 1);
                    float x  = vhi[j];
                    float xn = cs * x - sn * y;
                    float yn = sn * x + cs * y;
                    vhi[j] = xn;
                    float z = __shfl_up(yn, 1);
                    if (lam > 0) vlo[j] = z;
                }
            }
        }
    }

    const int t    = c0 >> 4;
    const int k0w  = lam >> 4;
    const int quad = (lam >> 2) & 3;
    u32* wtu = (u32*)wt;
#pragma unroll
    for (int j = 0; j < 4; j++) {
        __bf16 va = (__bf16)vlo[j];
        __bf16 vb = (__bf16)vhi[j];
        u32 pk = (u32)__builtin_bit_cast(unsigned short, va)
               | ((u32)__builtin_bit_cast(unsigned short, vb) << 16);
        const int frag = (t * 4 + k0w) * 64 + quad * 16 + ((c0 & 15) + j);
        wtu[mat * 8192 + frag * 4 + (lam & 3)] = pk;
    }
}

// ---------------------------------------------------------------------------
// 2) embed: 512 thr = 4 tokens/block (ew read once per block via L1).
//    LN0 -> hf (f32), hb (bf16 linear), invn = rsqrt(Sum h^2).
// ---------------------------------------------------------------------------
__global__ void __launch_bounds__(512)
embed_kernel(const float* __restrict__ x,  const float* __restrict__ ew,
             const float* __restrict__ eb, const float* __restrict__ ct,
             const float* __restrict__ g0, const float* __restrict__ b0,
             float* __restrict__ hf, __bf16* __restrict__ hb,
             float* __restrict__ invn)
{
    __shared__ float sx[4][48];
    __shared__ float sred[4][2];
    const int d  = threadIdx.x & 127, sq = threadIdx.x >> 7;
    const int wh = (threadIdx.x >> 6) & 1;
    const int b  = blockIdx.x & 127;
    const int s  = (blockIdx.x >> 7) * 4 + sq;

    if (s > 0 && d < 48) sx[sq][d] = x[(b * 127 + (s - 1)) * 48 + d];
    __syncthreads();

    float val;
    if (s == 0) {
        val = ct[d];
    } else {
        float aa = 0.f;
#pragma unroll
        for (int f = 0; f < 48; f++) aa = fmaf(sx[sq][f], ew[d * 48 + f], aa);
        val = aa + eb[d];
    }
    float v = val;
#pragma unroll
    for (int m = 32; m; m >>= 1) v += __shfl_xor(v, m);
    if ((threadIdx.x & 63) == 0) sred[sq][wh] = v;
    __syncthreads();
    float mean = (sred[sq][0] + sred[sq][1]) * (1.f / 128.f);
    float xc   = val - mean;
    __syncthreads();
    v = xc * xc;
#pragma unroll
    for (int m = 32; m; m >>= 1) v += __shfl_xor(v, m);
    if ((threadIdx.x & 63) == 0) sred[sq][wh] = v;
    __syncthreads();
    float var = (sred[sq][0] + sred[sq][1]) * (1.f / 128.f);
    float y   = xc * rsqrtf(var + 1e-5f) * g0[d] + b0[d];
    __syncthreads();
    v = y * y;
#pragma unroll
    for (int m = 32; m; m >>= 1) v += __shfl_xor(v, m);
    if ((threadIdx.x & 63) == 0) sred[sq][wh] = v;
    __syncthreads();
    float ss = sred[sq][0] + sred[sq][1];

    const int o = (b * 128 + s) * 128 + d;
    hf[o] = y;
    hb[o] = (__bf16)y;
    if (d == 0) invn[b * 128 + s] = rsqrtf(ss);
}

// ---------------------------------------------------------------------------
// 3) fused attention head (verbatim R13 body): one WG per (head, batch).
//    512 thr = 8 waves, wave w owns rows w*16..w*16+15.
//    A: T1 = h @ W   (A: sH, B: wt frags global) -> sY (wave-private)
//    B: G = T1 @ h^T (A: sY, B: sH), softmax -> Pm -> sY
//    C: V = h @ Vw^T (A: sH, B: cvwf frags global)
//    D: O = Pm @ V   (A: sY, B: sH=V^T), +h, LN, *mw -> hs
//    Barriers: B1 (stage), B4 (pre-V^T), B5 (post-V^T).
//    last==1: only wave 7 runs A/B/softmax/D; stores row 127.
// ---------------------------------------------------------------------------
__global__ void __launch_bounds__(512, 4)
attn_kernel(int l, int last,
            const float*  __restrict__ hf,  const __bf16* __restrict__ hb,
            const float*  __restrict__ invn, const __bf16* __restrict__ wt,
            const __bf16* __restrict__ vwf, const float* __restrict__ vb,
            const float* __restrict__ lng,  const float* __restrict__ lnb,
            const float* __restrict__ mwp,  __bf16* __restrict__ hs)
{
    __shared__ __align__(16) __bf16 sH[128 * 128];
    __shared__ __align__(16) __bf16 sY[128 * 128];
    __shared__ float sInv[128];
    __shared__ float sVb[128];
    __shared__ float sLg[128];
    __shared__ float sLb[128];

    const int tid  = threadIdx.x;
    const int lane = tid & 63, w = tid >> 6;
    const int l15  = lane & 15, quad = lane >> 4;
    const int b    = blockIdx.x & 127;   // XCD = b%8
    const int hh   = blockIdx.x >> 7;
    const int lh   = l * 8 + hh;

    const __bf16* hbp   = hb  + b * 16384;
    const __bf16* wbase = wt  + (size_t)lh * 16384;
    const __bf16* vbase = vwf + (size_t)lh * 16384;

    // ---- stage sH: async direct-to-LDS; linear dest, inverse-swz source ----
#pragma unroll
    for (int c = 0; c < 4; c++) {
        const int ch  = tid + c * 512;           // this lane's LDS chunk
        const int row = ch >> 4, cc = ch & 15;
        const int sc  = cc ^ (row & 15);         // inverse swizzle (involution)
        gll16(hbp + (row * 16 + sc) * 8, &sH[(c * 512 + w * 64) * 8]);
    }
    if (tid < 128) {
        sInv[tid] = invn[b * 128 + tid];
        sVb[tid]  = vb[lh * 128 + tid];
        sLg[tid]  = lng[lh * 128 + tid];
        sLb[tid]  = lnb[lh * 128 + tid];
    }
    __syncthreads();  // B1 (drains global_load_lds via vmcnt(0))

    const int r0 = w * 16;
    const int kq = quad * 8;
    const int q4 = quad * 4;
    const f32x4 vzero = {0.f, 0.f, 0.f, 0.f};
    const bool active = !last || (w == 7);

    f32x4 acc[8];

    // A-frags from sH (LDS), B-frags fragment-major from global -> acc
    auto mmGA = [&](const __bf16* gB) {
#pragma unroll
        for (int t = 0; t < 8; t++) acc[t] = vzero;
        __builtin_amdgcn_s_setprio(1);
#pragma unroll
        for (int k0c = 0; k0c < 4; k0c++) {
            bf16x8 a0 = *(const bf16x8*)(&sH[sidx(r0 + l15, k0c * 32 + kq)]);
#pragma unroll
            for (int t = 0; t < 8; t++) {
                bf16x8 bb = *(const bf16x8*)(gB + ((t * 4 + k0c) * 64 + lane) * 8);
                acc[t] = __builtin_amdgcn_mfma_f32_16x16x32_bf16(a0, bb, acc[t], 0, 0, 0);
            }
        }
        __builtin_amdgcn_s_setprio(0);
    };

    // A-frags from LDS (own rows), B-frags from LDS (all rows) -> acc
    auto mmLL = [&](const __bf16* Ab, const __bf16* Bb) {
#pragma unroll
        for (int t = 0; t < 8; t++) acc[t] = vzero;
        __builtin_amdgcn_s_setprio(1);
#pragma unroll
        for (int k0 = 0; k0 < 128; k0 += 32) {
            const int kk = k0 + kq;
            bf16x8 a0 = *(const bf16x8*)(&Ab[sidx(r0 + l15, kk)]);
#pragma unroll
            for (int t = 0; t < 8; t++) {
                bf16x8 bb = *(const bf16x8*)(&Bb[sidx(t * 16 + l15, kk)]);
                acc[t] = __builtin_amdgcn_mfma_f32_16x16x32_bf16(a0, bb, acc[t], 0, 0, 0);
            }
        }
        __builtin_amdgcn_s_setprio(0);
    };

    float hres[8][4];

    if (active) {
        // ========= Phase A: T1 = h @ W =========
        mmGA(wbase);
#pragma unroll
        for (int t = 0; t < 8; t++)
#pragma unroll
            for (int r = 0; r < 4; r++)
                sY[sidx(r0 + q4 + r, t * 16 + l15)] = (__bf16)acc[t][r];
        // no barrier: phase B reads only this wave's own T1 rows

        // ========= Phase B: G = T1 @ h^T =========
        mmLL(sY, sH);

        // ---- softmax (base 2): v = G^2*inv_s*inv_t*(scale*log2e) -> Pm ----
        {
            const float scale2 = 0.08838834764831843f * 1.4426950408889634f;
            float invt[8];
#pragma unroll
            for (int t = 0; t < 8; t++) invt[t] = sInv[t * 16 + l15];
            float invs[4];
#pragma unroll
            for (int r = 0; r < 4; r++) invs[r] = sInv[r0 + q4 + r];

            float mx[4] = {-3e38f, -3e38f, -3e38f, -3e38f};
#pragma unroll
            for (int t = 0; t < 8; t++)
#pragma unroll
                for (int r = 0; r < 4; r++) {
                    float g = acc[t][r];
                    float v = g * g * invs[r] * invt[t] * scale2;
                    acc[t][r] = v;
                    mx[r] = fmaxf(mx[r], v);
                }
#pragma unroll
            for (int m = 1; m < 16; m <<= 1)
#pragma unroll
                for (int r = 0; r < 4; r++) mx[r] = fmaxf(mx[r], __shfl_xor(mx[r], m));

            float sm[4] = {0.f, 0.f, 0.f, 0.f};
#pragma unroll
            for (int t = 0; t < 8; t++)
#pragma unroll
                for (int r = 0; r < 4; r++) {
                    float e = exp2f(acc[t][r] - mx[r]);
                    acc[t][r] = e;
                    sm[r] += e;
                }
#pragma unroll
            for (int m = 1; m < 16; m <<= 1)
#pragma unroll
                for (int r = 0; r < 4; r++) sm[r] += __shfl_xor(sm[r], m);
#pragma unroll
            for (int r = 0; r < 4; r++) sm[r] = 1.0f / sm[r];
#pragma unroll
            for (int t = 0; t < 8; t++)
#pragma unroll
                for (int r = 0; r < 4; r++)
                    sY[sidx(r0 + q4 + r, t * 16 + l15)] = (__bf16)(acc[t][r] * sm[r]);
        }

        // residual prefetch (consumed in epilogue)
        {
            const float* hfp = hf + (b * 128 + r0 + q4) * 128;
#pragma unroll
            for (int t = 0; t < 8; t++)
#pragma unroll
                for (int r = 0; r < 4; r++)
                    hres[t][r] = hfp[r * 128 + t * 16 + l15];
        }
    }

    // ========= Phase C: V = h @ Vw^T (all waves) =========
    mmGA(vbase);
    __syncthreads();  // B4: all waves done reading sH (phases B & C)

    {   // V^T into sH: sH[e][token]
        float vbv[8];
#pragma unroll
        for (int t = 0; t < 8; t++) vbv[t] = sVb[t * 16 + l15];
#pragma unroll
        for (int t = 0; t < 8; t++)
#pragma unroll
            for (int r = 0; r < 4; r++)
                sH[sidx(t * 16 + l15, r0 + q4 + r)] = (__bf16)(acc[t][r] + vbv[t]);
    }
    __syncthreads();  // B5

    if (active) {
        // ========= Phase D: O = Pm @ V =========
        mmLL(sY, sH);

        {   // epilogue: +h, LN over d, *merger_w -> hs
            const float mw = mwp[lh];
            float lgv[8], lbv[8];
#pragma unroll
            for (int t = 0; t < 8; t++) {
                lgv[t] = sLg[t * 16 + l15];
                lbv[t] = sLb[t * 16 + l15];
            }
            float sum_[4] = {0.f, 0.f, 0.f, 0.f};
            float sq_[4]  = {0.f, 0.f, 0.f, 0.f};
#pragma unroll
            for (int t = 0; t < 8; t++)
#pragma unroll
                for (int r = 0; r < 4; r++) {
                    float xx = acc[t][r] + hres[t][r];
                    acc[t][r] = xx;
                    sum_[r] += xx;
                    sq_[r]  += xx * xx;
                }
#pragma unroll
            for (int m = 1; m < 16; m <<= 1)
#pragma unroll
                for (int r = 0; r < 4; r++) {
                    sum_[r] += __shfl_xor(sum_[r], m);
                    sq_[r]  += __shfl_xor(sq_[r], m);
                }
            float mean[4], rstd[4];
#pragma unroll
            for (int r = 0; r < 4; r++) {
                mean[r] = sum_[r] * (1.f / 128.f);
                float var = sq_[r] * (1.f / 128.f) - mean[r] * mean[r];
                rstd[r] = rsqrtf(fmaxf(var, 0.f) + 1e-5f);
            }
            __bf16* hsp = hs + ((hh * 128 + b) * 128 + r0 + q4) * 128;
#pragma unroll
            for (int t = 0; t < 8; t++)
#pragma unroll
                for (int r = 0; r < 4; r++) {
                    if (!last || (q4 + r == 15)) {
                        float y = (acc[t][r] - mean[r]) * rstd[r] * lgv[t] + lbv[t];
                        hsp[r * 128 + t * 16 + l15] = (__bf16)(y * mw);
                    }
                }
        }
    }
}

// ---------------------------------------------------------------------------
// 4) merge v3 (vectorized): 16 lanes/token, 8 d/lane. 256 thr = 4 waves =
//    16 tokens/block. bf16x8 (16B) hs loads, float4 hf stores, 16B hb store.
//    Normal: grid 1024 (128 b x 8 s-groups). last: grid 8 (b-major, s=127,
//    writes out only).
// ---------------------------------------------------------------------------
__global__ void __launch_bounds__(256)
merge_kernel(const __bf16* __restrict__ hs, const float* __restrict__ mbp, int l,
             float* __restrict__ hf, __bf16* __restrict__ hb, float* __restrict__ invn,
             float* __restrict__ out, int last)
{
    const int lane = threadIdx.x & 63;
    const int wv   = threadIdx.x >> 6;
    const int sq   = lane >> 4;      // token within wave
    const int dl   = lane & 15;      // d-slice within token
    const int d0   = dl * 8;
    const float mbv = mbp[l];

    int b, s;
    if (last) {
        b = blockIdx.x * 16 + wv * 4 + sq;
        s = 127;
    } else {
        b = blockIdx.x & 127;
        s = (blockIdx.x >> 7) * 16 + wv * 4 + sq;
    }

    float a[8];
#pragma unroll
    for (int j = 0; j < 8; j++) a[j] = mbv;
#pragma unroll
    for (int h8 = 0; h8 < 8; h8++) {
        bf16x8 v = *(const bf16x8*)(hs + (((size_t)h8 * 128 + b) * 128 + s) * 128 + d0);
#pragma unroll
        for (int j = 0; j < 8; j++) a[j] += (float)v[j];
    }

    if (last) {
        float4 f0 = {a[0], a[1], a[2], a[3]};
        float4 f1 = {a[4], a[5], a[6], a[7]};
        *(float4*)(out + b * 128 + d0)     = f0;
        *(float4*)(out + b * 128 + d0 + 4) = f1;
        return;
    }

    float ss = 0.f;
#pragma unroll
    for (int j = 0; j < 8; j++) ss = fmaf(a[j], a[j], ss);
#pragma unroll
    for (int m = 1; m < 16; m <<= 1) ss += __shfl_xor(ss, m);  // Sum over 128 d

    const size_t o = ((size_t)b * 128 + s) * 128 + d0;
    float4 f0 = {a[0], a[1], a[2], a[3]};
    float4 f1 = {a[4], a[5], a[6], a[7]};
    *(float4*)(hf + o)     = f0;
    *(float4*)(hf + o + 4) = f1;

    u32 pk[4];
#pragma unroll
    for (int j2 = 0; j2 < 4; j2++) {
        __bf16 x0 = (__bf16)a[2 * j2], x1 = (__bf16)a[2 * j2 + 1];
        pk[j2] = (u32)__builtin_bit_cast(unsigned short, x0)
               | ((u32)__builtin_bit_cast(unsigned short, x1) << 16);
    }
    u32x4 pv = {pk[0], pk[1], pk[2], pk[3]};
    *(u32x4*)(hb + o) = pv;

    if (dl == 0) invn[b * 128 + s] = rsqrtf(ss);
}

// ---------------------------------------------------------------------------
extern "C" void kernel_launch(void* const* d_in, const int* in_sizes, int n_in,
                              void* d_out, int out_size, void* d_ws, size_t ws_size,
                              hipStream_t stream)
{
    (void)in_sizes; (void)n_in; (void)out_size; (void)ws_size;

    const float* x   = (const float*)d_in[0];
    const float* ew  = (const float*)d_in[1];
    const float* eb  = (const float*)d_in[2];
    const float* ct  = (const float*)d_in[3];
    const float* g0  = (const float*)d_in[4];
    const float* b0  = (const float*)d_in[5];
    const float* vw  = (const float*)d_in[6];
    const float* vb  = (const float*)d_in[7];
    const float* lng = (const float*)d_in[8];
    const float* lnb = (const float*)d_in[9];
    const float* phi = (const float*)d_in[10];
    const float* mw  = (const float*)d_in[11];
    const float* mb  = (const float*)d_in[12];
    float* out = (float*)d_out;

    char* ws = (char*)d_ws;
    __bf16* wt   = (__bf16*)(ws);                 //  1,572,864 (frag-major Wt)
    float*  hf   = (float*)(ws + 1572864);        //  8,388,608
    __bf16* hb   = (__bf16*)(ws + 9961472);       //  4,194,304 (linear bf16 h)
    float*  invn = (float*)(ws + 14155776);       //     65,536
    __bf16* hs   = (__bf16*)(ws + 14221312);      // 33,554,432
    __bf16* cvwf = (__bf16*)(ws + 47775744);      //  1,572,864 (frag-major Vw)
    float2* csn  = (float2*)(ws + 49348608);      //  6,291,456  (~55.6 MB)

    prep_kernel<<<3456, 256, 0, stream>>>(phi, csn, vw, cvwf);
    build_w_kernel<<<1536, 64, 0, stream>>>(csn, wt);
    embed_kernel<<<4096, 512, 0, stream>>>(x, ew, eb, ct, g0, b0, hf, hb, invn);
    for (int l = 0; l < 6; l++) {
        const int last = (l == 5) ? 1 : 0;
        attn_kernel<<<1024, 512, 0, stream>>>(l, last, hf, hb, invn, wt, cvwf,
                                              vb, lng, lnb, mw, hs);
        merge_kernel<<<last ? 8 : 1024, 256, 0, stream>>>(hs, mb, l, hf, hb,
                                                          invn, out, last);
    }
}